// Round 18
// baseline (328.979 us; speedup 1.0000x reference)
//
#include <hip/hip_runtime.h>
#include <math.h>

#define N_NODES 50000
#define E_REAL  200000
#define E_MEAN  250000   // real + self-loops (self handled densely in init)
#define NREL    65
#define HDIM    256
#define NGRAPH  1600
#define NB_R    ((E_REAL + 255) / 256)   // 782 blocks over REAL edges
#define NB_CNT  ((E_MEAN + 255) / 256)   // 977 blocks to also count self-loops
#define TOT_HIST (NREL * NB_R)           // 50830
#define MB      64                        // rows per MFMA tile
#define MAX_PB  3264                      // >= 65 + E_REAL/64 = 3190; divisible by 8
#define GRID_I  ((N_NODES + MB - 1) / MB) // 782 init tiles
#define NSA     ((TOT_HIST + 1023) / 1024)  // 50 scan blocks (region A)
#define NSB     ((N_NODES + 1023) / 1024)   // 49 scan blocks (region B)

typedef __attribute__((ext_vector_type(8))) short short8;   // 8 bf16 (4 VGPRs)
typedef __attribute__((ext_vector_type(4))) float floatx4;  // MFMA C/D frag
typedef const __attribute__((address_space(1))) void GPtr;
typedef __attribute__((address_space(3))) void LPtr;

__device__ __forceinline__ unsigned short f2bf(float f) {
    unsigned int u = __float_as_uint(f);
    unsigned int r = u + 0x7FFFu + ((u >> 16) & 1u);  // RNE
    return (unsigned short)(r >> 16);
}
__device__ __forceinline__ float bf2f(unsigned short u) {
    return __uint_as_float(((unsigned int)u) << 16);
}

// async global->LDS, 16B per lane; LDS dest must be wave-uniform base + lane*16
__device__ __forceinline__ void gl_lds16(const unsigned short* g, unsigned short* l) {
    __builtin_amdgcn_global_load_lds((GPtr*)g,
        (LPtr*)(unsigned int)(unsigned long long)(void*)l, 16, 0, 0);
}

// counts: cnt[d][r] over ALL edges (incl self, rel 0); blockHist/cntD over REAL only
__global__ void count_kernel(const int* __restrict__ src, const int* __restrict__ dst,
                             const int* __restrict__ et, int* __restrict__ cnt,
                             int* __restrict__ blockHist, int* __restrict__ cntD) {
    __shared__ int lhist[NREL];
    int t = threadIdx.x;
    if (t < NREL) lhist[t] = 0;
    __syncthreads();
    int e = blockIdx.x * 256 + t;
    if (e < E_REAL) {
        int d = dst[e], r = et[e];
        atomicAdd(&cnt[d * NREL + r], 1);
        atomicAdd(&cntD[d], 1);
        atomicAdd(&lhist[r], 1);
    } else if (e < E_MEAN) {
        atomicAdd(&cnt[(e - E_REAL) * NREL], 1);   // self-loop, rel 0
    }
    __syncthreads();
    if (t < NREL && blockIdx.x < NB_R) blockHist[t * NB_R + blockIdx.x] = lhist[t];
}

// combined hierarchical scan, phase 1
__global__ void scan_part2(const int* __restrict__ inA, const int* __restrict__ inB,
                           int* __restrict__ psumA, int* __restrict__ psumB) {
    __shared__ int red[1024];
    int t = threadIdx.x;
    int b = blockIdx.x;
    const int* in; int n; int bi;
    if (b < NSA) { in = inA; n = TOT_HIST; bi = b; }
    else         { in = inB; n = N_NODES;  bi = b - NSA; }
    int g = bi * 1024 + t;
    red[t] = (g < n) ? in[g] : 0;
    __syncthreads();
    for (int off = 512; off >= 1; off >>= 1) {
        if (t < off) red[t] += red[t + off];
        __syncthreads();
    }
    if (t == 0) {
        if (b < NSA) psumA[bi] = red[0];
        else         psumB[bi] = red[0];
    }
}

// combined phase 2: exclusive scan both regions; B region also fills out2 (cursor)
__global__ void scan_apply2(const int* __restrict__ inA, const int* __restrict__ inB,
                            const int* __restrict__ psumA, const int* __restrict__ psumB,
                            int* __restrict__ outA, int* __restrict__ outB,
                            int* __restrict__ outB2) {
    __shared__ int sums[1024];
    __shared__ int soff;
    int t = threadIdx.x;
    int b = blockIdx.x;
    const int* in; const int* ps; int n; int bi;
    if (b < NSA) { in = inA; ps = psumA; n = TOT_HIST; bi = b; }
    else         { in = inB; ps = psumB; n = N_NODES;  bi = b - NSA; }
    if (t < 64) {
        int v = (t < bi) ? ps[t] : 0;
        for (int off = 32; off >= 1; off >>= 1) v += __shfl_down(v, off, 64);
        if (t == 0) soff = v;
    }
    int g = bi * 1024 + t;
    int v = (g < n) ? in[g] : 0;
    sums[t] = v;
    __syncthreads();
    for (int off = 1; off < 1024; off <<= 1) {
        int u = (t >= off) ? sums[t - off] : 0;
        __syncthreads();
        sums[t] += u;
        __syncthreads();
    }
    if (g < n) {
        int excl = soff + sums[t] - v;
        if (b < NSA) outA[g] = excl;
        else { outB[g] = excl; outB2[g] = excl; }
    }
}

// relation segment metadata (64-granule tiles)
__global__ void meta_kernel(const int* __restrict__ baseArr,
                            int* __restrict__ relStart, int* __restrict__ relTot,
                            int* __restrict__ pBlockStart, int* __restrict__ relOfBlock,
                            int* __restrict__ npb) {
    __shared__ int sStart[NREL + 1];
    __shared__ int sPB[NREL + 1];
    int t = threadIdx.x;
    if (t < NREL) sStart[t] = baseArr[t * NB_R];
    if (t == 0) sStart[NREL] = E_REAL;
    __syncthreads();
    if (t < NREL) {
        relStart[t] = sStart[t];
        relTot[t] = sStart[t + 1] - sStart[t];
    }
    if (t == 0) {
        int a2 = 0;
        for (int r = 0; r < NREL; ++r) {
            sPB[r] = a2;
            int tot = sStart[r + 1] - sStart[r];
            a2 += (tot + MB - 1) / MB;
        }
        sPB[NREL] = a2;
        npb[0] = a2;
    }
    __syncthreads();
    if (t < NREL) pBlockStart[t] = sPB[t];
    int NPB = sPB[NREL];
    for (int b = t; b < NPB; b += 1024) {
        int lo = 0, hi = NREL - 1;
        while (lo < hi) { int mid = (lo + hi + 1) >> 1; if (sPB[mid] <= b) lo = mid; else hi = mid - 1; }
        relOfBlock[b] = lo;
    }
}

// counting-sort scatter by relation (REAL edges). Besides perm/qofp, precompute
// per-slot edge metadata (srcOf, wOf) so the edge GEMM's meta phase is three
// coalesced loads with no dependent random-load chain (cnt is complete here).
__global__ void scatter_sorted(const int* __restrict__ src, const int* __restrict__ dst,
                               const int* __restrict__ et, const int* __restrict__ base,
                               const int* __restrict__ cnt,
                               int* __restrict__ perm, int* __restrict__ cursorD,
                               int* __restrict__ qofp, int* __restrict__ srcOf,
                               float* __restrict__ wOf) {
    __shared__ int lhist[NREL];
    int t = threadIdx.x;
    int b = blockIdx.x;
    if (t < NREL) lhist[t] = 0;
    __syncthreads();
    int e = b * 256 + t;
    if (e < E_REAL) {
        int d = dst[e], r = et[e];
        int local = atomicAdd(&lhist[r], 1);
        int p = base[r * NB_R + b] + local;
        perm[p] = e;
        int q = atomicAdd(&cursorD[d], 1);
        qofp[p] = q;
        srcOf[p] = src[e];
        wOf[p] = 1.0f / (float)cnt[d * NREL + r];
    }
}

// --- conversion helpers (device) ---
__device__ __forceinline__ void cvt_row_chunk(const float* __restrict__ in,
                                              unsigned short* __restrict__ out,
                                              int i, int relu) {
    const float4* p = (const float4*)in + (size_t)i * 2;
    float4 a = p[0], b = p[1];
    float v[8] = {a.x, a.y, a.z, a.w, b.x, b.y, b.z, b.w};
    short8 o;
#pragma unroll
    for (int j = 0; j < 8; ++j) {
        float f = relu ? fmaxf(v[j], 0.f) : v[j];
        o[j] = (short)f2bf(f);
    }
    ((short8*)out)[i] = o;
}
__device__ __forceinline__ void cvt_wT_chunk(const float* __restrict__ W,
                                             unsigned short* __restrict__ out,
                                             int i, int K, int N) {
    int kc8 = K / 8;
    int kc = i % kc8;
    int tmp = i / kc8;
    int n = tmp % N;
    int r = tmp / N;
    const float* src = W + ((size_t)r * K + kc * 8) * N + n;
    short8 o;
#pragma unroll
    for (int j = 0; j < 8; ++j) o[j] = (short)f2bf(src[(size_t)j * N]);
    ((short8*)out)[i] = o;
}

// fp32 row-major -> bf16 row-major, optional relu (standalone, fallback path)
__global__ void cvt_rows(const float* __restrict__ in, unsigned short* __restrict__ out,
                         int nchunk, int relu) {
    int i = blockIdx.x * 256 + threadIdx.x;
    if (i >= nchunk) return;
    cvt_row_chunk(in, out, i, relu);
}

// all five conversions in one dispatch
#define CVT_NX  (N_NODES * 128 / 8)          // 800000
#define CVT_W1  (NREL * 256 * 16)            // 266240
#define CVT_W2  (NREL * 256 * 32)            // 532480
#define CVT_R1  (256 * 16)                   // 4096
#define CVT_R2  (256 * 32)                   // 8192
#define CVT_TOT (CVT_NX + CVT_W1 + CVT_W2 + CVT_R1 + CVT_R2)
__global__ void cvt_all(const float* __restrict__ x, const float* __restrict__ W1,
                        const float* __restrict__ W2, const float* __restrict__ root1,
                        const float* __restrict__ root2,
                        unsigned short* __restrict__ xb, unsigned short* __restrict__ w1b,
                        unsigned short* __restrict__ w2b, unsigned short* __restrict__ r1b,
                        unsigned short* __restrict__ r2b) {
    int i = blockIdx.x * 256 + threadIdx.x;
    if (i < CVT_NX) { cvt_row_chunk(x, xb, i, 0); return; }
    i -= CVT_NX;
    if (i < CVT_W1) { cvt_wT_chunk(W1, w1b, i, 128, 256); return; }
    i -= CVT_W1;
    if (i < CVT_W2) { cvt_wT_chunk(W2, w2b, i, 256, 256); return; }
    i -= CVT_W2;
    if (i < CVT_R1) { cvt_wT_chunk(root1, r1b, i, 128, 256); return; }
    i -= CVT_R1;
    if (i < CVT_R2) { cvt_wT_chunk(root2, r2b, i, 256, 256); return; }
}

// B-ring warm-up at a K-offset
template<int K>
__device__ __forceinline__ void ring_init_off(const unsigned short* __restrict__ Bp,
                                              int koff, int lrow, int lk,
                                              short8 (&b0)[4], short8 (&b1)[4]) {
#pragma unroll
    for (int nf = 0; nf < 4; ++nf)
        b0[nf] = *(const short8*)(Bp + (size_t)(nf * 16 + lrow) * K + koff + lk * 8);
#pragma unroll
    for (int nf = 0; nf < 4; ++nf)
        b1[nf] = *(const short8*)(Bp + (size_t)(nf * 16 + lrow) * K + koff + 32 + lk * 8);
}

// full-tile K-sweep with pre-loaded ring (row stride K)
template<int K>
__device__ __forceinline__ void gemm_main(const unsigned short* __restrict__ Bp,
                                          const unsigned short* lds,
                                          int lrow, int lk,
                                          short8 (&b0)[4], short8 (&b1)[4],
                                          floatx4 (&acc)[4][4]) {
    constexpr int KS = K / 32;
    short8 bb[3][4];
#pragma unroll
    for (int nf = 0; nf < 4; ++nf) { bb[0][nf] = b0[nf]; bb[1][nf] = b1[nf]; }
#pragma unroll
    for (int ks = 0; ks < KS; ++ks) {
        short8 a[4];
#pragma unroll
        for (int mf = 0; mf < 4; ++mf) {
            int row = mf * 16 + lrow;
            int c = (ks * 4 + lk) ^ (row & 7);
            a[mf] = *(const short8*)((const char*)lds + row * (K * 2) + c * 16);
        }
        if (ks + 2 < KS) {
#pragma unroll
            for (int nf = 0; nf < 4; ++nf)
                bb[(ks + 2) % 3][nf] = *(const short8*)(Bp + (size_t)(nf * 16 + lrow) * K + (ks + 2) * 32 + lk * 8);
        }
#pragma unroll
        for (int mf = 0; mf < 4; ++mf)
#pragma unroll
            for (int nf = 0; nf < 4; ++nf)
                acc[mf][nf] = __builtin_amdgcn_mfma_f32_16x16x32_bf16(a[mf], bb[ks % 3][nf], acc[mf][nf], 0, 0, 0);
    }
}

// classic one-call K-sweep (ring loaded inline)
template<int K>
__device__ __forceinline__ void gemm_pass(const unsigned short* __restrict__ Bp,
                                          const unsigned short* lds,
                                          int lrow, int lk, floatx4 (&acc)[4][4]) {
    short8 b0[4], b1[4];
    ring_init_off<K>(Bp, 0, lrow, lk, b0, b1);
    gemm_main<K>(Bp, lds, lrow, lk, b0, b1, acc);
}

// half-tile K-sweep: KH = K/64 K-steps from a compact half buffer (row stride K/2)
template<int K>
__device__ __forceinline__ void gemm_half(const unsigned short* __restrict__ Bp,
                                          int koff, const unsigned short* buf,
                                          int lrow, int lk,
                                          short8 (&b0)[4], short8 (&b1)[4],
                                          floatx4 (&acc)[4][4]) {
    constexpr int KH = K / 64;       // K-steps per half
    constexpr int CH2 = K / 16;      // 16B chunks per row per half
    short8 bb[3][4];
#pragma unroll
    for (int nf = 0; nf < 4; ++nf) { bb[0][nf] = b0[nf]; bb[1][nf] = b1[nf]; }
#pragma unroll
    for (int ks2 = 0; ks2 < KH; ++ks2) {
        short8 a[4];
#pragma unroll
        for (int mf = 0; mf < 4; ++mf) {
            int row = mf * 16 + lrow;
            int c = (ks2 * 4 + lk) ^ (row & 7);
            a[mf] = *(const short8*)(buf + (row * CH2 + c) * 8);
        }
        if (ks2 + 2 < KH) {
#pragma unroll
            for (int nf = 0; nf < 4; ++nf)
                bb[(ks2 + 2) % 3][nf] = *(const short8*)(Bp + (size_t)(nf * 16 + lrow) * K + koff + (ks2 + 2) * 32 + lk * 8);
        }
#pragma unroll
        for (int mf = 0; mf < 4; ++mf)
#pragma unroll
            for (int nf = 0; nf < 4; ++nf)
                acc[mf][nf] = __builtin_amdgcn_mfma_f32_16x16x32_bf16(a[mf], bb[ks2 % 3][nf], acc[mf][nf], 0, 0, 0);
    }
}

// stage one K-half; per-row src node via register+shfl (UNIFORM loop — safe)
template<int K>
__device__ __forceinline__ void stage_half_r(const unsigned short* __restrict__ A,
                                             unsigned short* buf, int sreg,
                                             int h, int t) {
    constexpr int CH2 = K / 16;
#pragma unroll
    for (int i = 0; i < (MB * CH2) / 256; ++i) {
        int q = i * 256 + t;
        int row = q / CH2, sl = q % CH2;
        int srow = __shfl(sreg, row, 64);
        int cg = h * CH2 + (sl ^ (row & 7));
        gl_lds16(A + (size_t)srow * K + cg * 8, buf + q * 8);
    }
}

// async full-tile A-staging, src via register+shfl (UNIFORM loop — safe)
template<int K>
__device__ __forceinline__ void stage_A_r(const unsigned short* __restrict__ A,
                                          unsigned short* lds, int sreg, int t) {
    constexpr int CH = K / 8;
#pragma unroll
    for (int i = 0; i < (MB * CH) / 256; ++i) {
        int q = i * 256 + t;
        int row = q / CH, sl = q % CH;
        int srow = __shfl(sreg, row, 64);
        int cg = sl ^ (row & 7);
        gl_lds16(A + (size_t)srow * K + cg * 8, lds + q * 8);
    }
}

// async full-tile A-staging (LDS meta variant, fallback path)
template<int K, bool EDGE>
__device__ __forceinline__ void stage_A(const unsigned short* __restrict__ A,
                                        unsigned short* lds, const int* ssrc,
                                        int rowbase, int t) {
    constexpr int CH = K / 8;
#pragma unroll
    for (int i = 0; i < (MB * CH) / 256; ++i) {
        int q = i * 256 + t;
        int row = q / CH, sl = q % CH;
        int srow;
        if constexpr (EDGE) srow = ssrc[row];
        else { srow = rowbase + row; if (srow >= N_NODES) srow = N_NODES - 1; }
        int cg = sl ^ (row & 7);
        gl_lds16(A + (size_t)srow * K + cg * 8, lds + q * 8);
    }
}

// EDGE message GEMM. K=256: split-K half-staged pipeline. K=128: full-tile.
// XCD-chunked block swizzle. Meta in REGISTERS (shfl-indexed): LDS is exactly
// 32KB -> 5 blocks/CU. All shfl uses are in UNIFORM loops (store loop runs a
// fixed 8 iterations with a predicated store — divergent-shfl hazard fixed).
template<int K>
__global__ __launch_bounds__(256) void edge_msg(
    const unsigned short* __restrict__ A,   // [*][K] bf16 rows
    const unsigned short* __restrict__ B,   // [R][256][K] bf16 (transposed)
    unsigned short* __restrict__ outB,      // msg rows
    const int* __restrict__ srcOf, const float* __restrict__ wOf,
    const int* __restrict__ qofp,
    const int* __restrict__ relOfBlock, const int* __restrict__ pBlockStart,
    const int* __restrict__ relStart, const int* __restrict__ relTot,
    const int* __restrict__ npb)
{
    __shared__ __align__(16) unsigned short lds[MB * HDIM];  // exactly 32768 B
    int t = threadIdx.x;
    int lane = t & 63;
    // XCD-chunked bijective swizzle (MAX_PB % 8 == 0)
    int b = (blockIdx.x & 7) * (MAX_PB / 8) + (blockIdx.x >> 3);
    if (b >= npb[0]) return;
    int rel = relOfBlock[b];
    int jb = b - pBlockStart[rel];
    int rs = relStart[rel];
    int nval = relTot[rel] - jb * MB; if (nval > MB) nval = MB;
    // per-lane meta registers (each wave holds the block's 64 slots)
    int mS = 0, mQ = 0; float mW = 0.f;
    if (lane < nval) {
        int p = rs + jb * MB + lane;
        mS = srcOf[p];
        mQ = qofp[p];
        mW = wOf[p];
    }

    int wave = t >> 6;
    int n0 = wave * 64;
    int lrow = lane & 15, lk = lane >> 4;
    const unsigned short* Bp = B + ((size_t)rel * HDIM + n0) * K;

    floatx4 acc[4][4];
#pragma unroll
    for (int mf = 0; mf < 4; ++mf)
#pragma unroll
        for (int nf = 0; nf < 4; ++nf) acc[mf][nf] = (floatx4)0.f;

    if constexpr (K == 256) {
        constexpr int CH2 = K / 16;
        constexpr int HELEM = MB * CH2 * 8;
        unsigned short* buf0 = lds;
        unsigned short* buf1 = lds + HELEM;
        stage_half_r<K>(A, buf0, mS, 0, t);
        short8 b0[4], b1[4];
        ring_init_off<K>(Bp, 0, lrow, lk, b0, b1);   // overlaps the half0 drain
        __syncthreads();                              // drains half0
        stage_half_r<K>(A, buf1, mS, 1, t);           // async: hides under phase 0
        gemm_half<K>(Bp, 0, buf0, lrow, lk, b0, b1, acc);      // phase 0
        ring_init_off<K>(Bp, K / 2, lrow, lk, b0, b1);         // phase-1 ring under drain
        __syncthreads();                              // drains half1 (mostly covered)
        gemm_half<K>(Bp, K / 2, buf1, lrow, lk, b0, b1, acc);  // phase 1
    } else {
        stage_A_r<K>(A, lds, mS, t);
        short8 b0[4], b1[4];
        ring_init_off<K>(Bp, 0, lrow, lk, b0, b1);   // overlaps the staging drain
        __syncthreads();
        gemm_main<K>(Bp, lds, lrow, lk, b0, b1, acc);
    }

    __syncthreads();  // all A reads done; reuse lds as pack
#pragma unroll
    for (int mf = 0; mf < 4; ++mf) {
        int mbase = mf * 16 + lk * 4;
#pragma unroll
        for (int i = 0; i < 4; ++i) {
            int row = mbase + i;
            float w = __shfl(mW, row, 64);
#pragma unroll
            for (int nf = 0; nf < 4; ++nf)
                lds[row * HDIM + n0 + nf * 16 + lrow] = f2bf(acc[mf][nf][i] * w);
        }
    }
    __syncthreads();
    // UNIFORM store loop: 8 fixed iterations; shfl by the full wave; store predicated
#pragma unroll
    for (int i = 0; i < (MB * 32) / 256; ++i) {
        int q = i * 256 + t;
        int row = q >> 5, c = q & 31;
        int qd = __shfl(mQ, row, 64);
        if (row < nval)
            *(uint4*)(outB + (size_t)qd * HDIM + c * 8) = *(const uint4*)(lds + row * HDIM + c * 8);
    }
}

// INIT dense GEMM: hinit = bf16( A@root + bias + (A@W0)*(1/cnt[d,0]) )
// sw in registers (shfl) -> LDS exactly 32KB -> 5 blocks/CU.
template<int K>
__global__ __launch_bounds__(256) void init_gemm(
    const unsigned short* __restrict__ A,
    const unsigned short* __restrict__ Broot,  // [256][K] root panel
    const unsigned short* __restrict__ Bself,  // W[0] panel
    const float* __restrict__ bias,
    unsigned short* __restrict__ outB,
    const int* __restrict__ cnt)
{
    __shared__ __align__(16) unsigned short lds[MB * HDIM];  // exactly 32768 B
    int t = threadIdx.x;
    int lane = t & 63;
    int rowbase = blockIdx.x * MB;
    float mW;
    {
        int srow = rowbase + lane; if (srow >= N_NODES) srow = N_NODES - 1;
        mW = 1.0f / (float)cnt[srow * NREL];   // 1/cnt[d,0] for self term
    }
    int wave = t >> 6;
    int n0 = wave * 64;
    int lrow = lane & 15, lk = lane >> 4;

    stage_A<K, false>(A, lds, nullptr, rowbase, t);
    short8 b0[4], b1[4];
    ring_init_off<K>(Bself + (size_t)n0 * K, 0, lrow, lk, b0, b1);  // overlaps drain
    __syncthreads();

    floatx4 acc[4][4];
#pragma unroll
    for (int mf = 0; mf < 4; ++mf)
#pragma unroll
        for (int nf = 0; nf < 4; ++nf) acc[mf][nf] = (floatx4)0.f;
    // pass 1: self W0; scale per-row; pass 2: root into same acc
    gemm_main<K>(Bself + (size_t)n0 * K, lds, lrow, lk, b0, b1, acc);
#pragma unroll
    for (int mf = 0; mf < 4; ++mf) {
        int mbase = mf * 16 + lk * 4;
#pragma unroll
        for (int i = 0; i < 4; ++i) {
            float w = __shfl(mW, mbase + i, 64);
#pragma unroll
            for (int nf = 0; nf < 4; ++nf) acc[mf][nf][i] *= w;
        }
    }
    gemm_pass<K>(Broot + (size_t)n0 * K, lds, lrow, lk, acc);

    float bv[4];
#pragma unroll
    for (int nf = 0; nf < 4; ++nf) bv[nf] = bias[n0 + nf * 16 + lrow];
    __syncthreads();  // A reads done; reuse lds as pack
#pragma unroll
    for (int mf = 0; mf < 4; ++mf) {
        int mbase = mf * 16 + lk * 4;
#pragma unroll
        for (int i = 0; i < 4; ++i) {
            int row = mbase + i;
#pragma unroll
            for (int nf = 0; nf < 4; ++nf)
                lds[row * HDIM + n0 + nf * 16 + lrow] = f2bf(acc[mf][nf][i] + bv[nf]);
        }
    }
    __syncthreads();
    int limit = N_NODES - rowbase; if (limit > MB) limit = MB;
    for (int q = t; q < limit * 32; q += 256) {     // no shfl inside: safe
        int row = q >> 5, c = q & 31;
        *(uint4*)(outB + ((size_t)rowbase + row) * HDIM + c * 8) = *(const uint4*)(lds + row * HDIM + c * 8);
    }
}

// fallback MFMA GEMM (round-3 proven path)
template<int K, int MODE>
__global__ __launch_bounds__(256) void mfma_gemm(
    const unsigned short* __restrict__ A,
    const unsigned short* __restrict__ B,
    const unsigned short* __restrict__ Bself,
    const float* __restrict__ bias,
    float* __restrict__ outF,
    const int* __restrict__ perm, const int* __restrict__ srcA,
    const int* __restrict__ dstA, const int* __restrict__ cnt,
    const int* __restrict__ relOfBlock, const int* __restrict__ pBlockStart,
    const int* __restrict__ relStart, const int* __restrict__ relTot,
    const int* __restrict__ npb)
{
    constexpr bool EDGE = (MODE == 1);
    __shared__ __align__(16) unsigned short lds[MB * HDIM];
    __shared__ int ssrc[MB];
    __shared__ int sdst[MB];
    __shared__ float sw[MB];
    int t = threadIdx.x;
    int b = blockIdx.x;
    int rel = 0, rowbase = 0, jb = 0, rs = 0, nval = MB;
    if constexpr (EDGE) {
        if (b >= npb[0]) return;
        rel = relOfBlock[b];
        jb = b - pBlockStart[rel];
        rs = relStart[rel];
        nval = relTot[rel] - jb * MB; if (nval > MB) nval = MB;
        if (t < MB) {
            int s = 0, d = 0; float w = 0.f;
            if (t < nval) {
                int p = rs + jb * MB + t;
                int e = perm[p];
                s = srcA[e]; d = dstA[e];
                w = 1.0f / (float)cnt[d * NREL + rel];
            }
            ssrc[t] = s; sdst[t] = d; sw[t] = w;
        }
        __syncthreads();
    } else {
        rowbase = b * MB;
        if (t < MB) {
            int srow = rowbase + t; if (srow >= N_NODES) srow = N_NODES - 1;
            sw[t] = 1.0f / (float)cnt[srow * NREL];
        }
    }
    stage_A<K, EDGE>(A, lds, ssrc, rowbase, t);
    __syncthreads();

    int wave = t >> 6, lane = t & 63;
    int n0 = wave * 64;
    int lrow = lane & 15;
    int lk = lane >> 4;
    floatx4 acc[4][4];
#pragma unroll
    for (int mf = 0; mf < 4; ++mf)
#pragma unroll
        for (int nf = 0; nf < 4; ++nf) acc[mf][nf] = (floatx4)0.f;

    if constexpr (EDGE) {
        gemm_pass<K>(B + ((size_t)rel * HDIM + n0) * K, lds, lrow, lk, acc);
    } else {
        gemm_pass<K>(Bself + (size_t)n0 * K, lds, lrow, lk, acc);
#pragma unroll
        for (int mf = 0; mf < 4; ++mf) {
            int mbase = mf * 16 + lk * 4;
#pragma unroll
            for (int i = 0; i < 4; ++i) {
                float w = sw[mbase + i];
#pragma unroll
                for (int nf = 0; nf < 4; ++nf) acc[mf][nf][i] *= w;
            }
        }
        gemm_pass<K>(B + (size_t)n0 * K, lds, lrow, lk, acc);
    }

    if constexpr (MODE == 1) {
#pragma unroll
        for (int mf = 0; mf < 4; ++mf) {
            int mbase = mf * 16 + lk * 4;
#pragma unroll
            for (int i = 0; i < 4; ++i) {
                int mm = mbase + i;
                float w = sw[mm];
                if (w != 0.f) {
                    int drow = sdst[mm];
#pragma unroll
                    for (int nf = 0; nf < 4; ++nf) {
                        int col = n0 + nf * 16 + lrow;
                        atomicAdd(&outF[(size_t)drow * HDIM + col], acc[mf][nf][i] * w);
                    }
                }
            }
        }
    } else {
        float bv[4];
#pragma unroll
        for (int nf = 0; nf < 4; ++nf) bv[nf] = bias[n0 + nf * 16 + lrow];
#pragma unroll
        for (int mf = 0; mf < 4; ++mf) {
            int mbase = mf * 16 + lk * 4;
#pragma unroll
            for (int i = 0; i < 4; ++i) {
                int mm = rowbase + mbase + i;
                if (mm < N_NODES) {
#pragma unroll
                    for (int nf = 0; nf < 4; ++nf) {
                        int col = n0 + nf * 16 + lrow;
                        outF[(size_t)mm * HDIM + col] = acc[mf][nf][i] + bv[nf];
                    }
                }
            }
        }
    }
}

// layer-1 gather-reduce: msg rows for dst d are CONTIGUOUS [startD[d], +cntD[d]).
// 16B/lane: 32 lanes per dst (row = 512B = 32 x 16B), 8 dsts per block.
__global__ __launch_bounds__(256) void reduce_kernel(
    const unsigned short* __restrict__ hinit, const unsigned short* __restrict__ msg,
    const int* __restrict__ startD, const int* __restrict__ cntD,
    unsigned short* __restrict__ hout)
{
    int t = threadIdx.x;
    int lane = t & 63;
    int d = blockIdx.x * 8 + ((t >> 6) << 1) + (lane >> 5);
    if (d >= N_NODES) return;
    int sl = lane & 31;
    int s0 = startD[d], n = cntD[d];
    short8 hv = *(const short8*)(hinit + (size_t)d * HDIM + sl * 8);
    float v[8];
#pragma unroll
    for (int j = 0; j < 8; ++j) v[j] = bf2f((unsigned short)hv[j]);
    const unsigned short* mp = msg + (size_t)s0 * HDIM + sl * 8;
#pragma unroll 4
    for (int q = 0; q < n; ++q) {
        short8 m = *(const short8*)(mp + (size_t)q * HDIM);
#pragma unroll
        for (int j = 0; j < 8; ++j) v[j] += bf2f((unsigned short)m[j]);
    }
    short8 o;
#pragma unroll
    for (int j = 0; j < 8; ++j) o[j] = (short)f2bf(fmaxf(v[j], 0.f));
    *(short8*)(hout + (size_t)d * HDIM + sl * 8) = o;
}

// FUSED layer-2 reduce + weighted-sum pooling (atomic-free; h2 never materialized)
__global__ __launch_bounds__(256) void reduce_pool(
    const unsigned short* __restrict__ hinit, const unsigned short* __restrict__ msg,
    const int* __restrict__ startD, const int* __restrict__ cntD,
    const int* __restrict__ batch, const float* __restrict__ wsw,
    const float* __restrict__ wsb, float* __restrict__ emb)
{
    int g = blockIdx.x;
    int t = threadIdx.x;
    __shared__ int slo, shi;
    __shared__ float sacc[4][HDIM];
    if (t == 0) {
        int lo = 0, hi = N_NODES;
        while (lo < hi) { int m = (lo + hi) >> 1; if (batch[m] < g) lo = m + 1; else hi = m; }
        slo = lo;
        int lo2 = lo, hi2 = N_NODES;
        while (lo2 < hi2) { int m = (lo2 + hi2) >> 1; if (batch[m] < g + 1) lo2 = m + 1; else hi2 = m; }
        shi = lo2;
    }
    __syncthreads();
    int wave = t >> 6, lane = t & 63;
    float4 wv = *(const float4*)(wsw + lane * 4);
    float wb = wsb[0];
    float a0 = 0.f, a1 = 0.f, a2 = 0.f, a3 = 0.f;
    for (int d = slo + wave; d < shi; d += 4) {
        int s0 = startD[d], n = cntD[d];
        ushort4 hv = *(const ushort4*)(hinit + (size_t)d * HDIM + lane * 4);
        float v0 = bf2f(hv.x), v1 = bf2f(hv.y), v2 = bf2f(hv.z), v3 = bf2f(hv.w);
        const unsigned short* mp = msg + (size_t)s0 * HDIM + lane * 4;
        for (int q = 0; q < n; ++q) {
            ushort4 m = *(const ushort4*)(mp + (size_t)q * HDIM);
            v0 += bf2f(m.x); v1 += bf2f(m.y); v2 += bf2f(m.z); v3 += bf2f(m.w);
        }
        v0 = fmaxf(v0, 0.f); v1 = fmaxf(v1, 0.f);
        v2 = fmaxf(v2, 0.f); v3 = fmaxf(v3, 0.f);
        float pp = v0 * wv.x + v1 * wv.y + v2 * wv.z + v3 * wv.w;
        for (int off = 32; off >= 1; off >>= 1) pp += __shfl_down(pp, off, 64);
        float tot = __shfl(pp, 0, 64);
        float sig = 1.0f / (1.0f + expf(-(tot + wb)));
        a0 += sig * v0; a1 += sig * v1; a2 += sig * v2; a3 += sig * v3;
    }
    sacc[wave][lane * 4 + 0] = a0; sacc[wave][lane * 4 + 1] = a1;
    sacc[wave][lane * 4 + 2] = a2; sacc[wave][lane * 4 + 3] = a3;
    __syncthreads();
    emb[(size_t)g * HDIM + t] = sacc[0][t] + sacc[1][t] + sacc[2][t] + sacc[3][t];
}

// fallback pool (fp32 h input)
__global__ void pool_kernel(const float* __restrict__ h, const int* __restrict__ batch,
                            const float* __restrict__ wsw, const float* __restrict__ wsb,
                            float* __restrict__ emb) {
    int i = blockIdx.x;
    int t = threadIdx.x;
    float v = fmaxf(h[(size_t)i * HDIM + t], 0.f);
    float p = v * wsw[t];
    for (int off = 32; off >= 1; off >>= 1) p += __shfl_down(p, off, 64);
    __shared__ float red[4];
    __shared__ float ssig;
    if ((t & 63) == 0) red[t >> 6] = p;
    __syncthreads();
    if (t == 0) {
        float s = red[0] + red[1] + red[2] + red[3] + wsb[0];
        ssig = 1.0f / (1.0f + expf(-s));
    }
    __syncthreads();
    atomicAdd(&emb[(size_t)batch[i] * HDIM + t], ssig * v);
}

__global__ void mlp_kernel(const float* __restrict__ emb,
                           const float* __restrict__ m1w, const float* __restrict__ m1b,
                           const float* __restrict__ m2w, const float* __restrict__ m2b,
                           const float* __restrict__ m3w, const float* __restrict__ m3b,
                           const float* __restrict__ ow,  const float* __restrict__ ob,
                           float* __restrict__ out) {
    int g = blockIdx.x;
    int t = threadIdx.x; // 64 threads = 1 wave
    __shared__ float e[HDIM];
    __shared__ float z1[64], z2[64];
    for (int idx = t; idx < HDIM; idx += 64) e[idx] = emb[(size_t)g * HDIM + idx];
    __syncthreads();
    float a = m1b[t];
    for (int k = 0; k < HDIM; ++k) a += e[k] * m1w[k * 64 + t];
    z1[t] = fmaxf(a, 0.f);
    __syncthreads();
    a = m2b[t];
    for (int k = 0; k < 64; ++k) a += z1[k] * m2w[k * 64 + t];
    z2[t] = fmaxf(a, 0.f);
    __syncthreads();
    a = m3b[t];
    for (int k = 0; k < 64; ++k) a += z2[k] * m3w[k * 64 + t];
    float p = a * ow[t];
    for (int off = 32; off >= 1; off >>= 1) p += __shfl_down(p, off, 64);
    if (t == 0) out[g] = p + ob[0];
}

extern "C" void kernel_launch(void* const* d_in, const int* in_sizes, int n_in,
                              void* d_out, int out_size, void* d_ws, size_t ws_size,
                              hipStream_t stream) {
    const float* x     = (const float*)d_in[0];
    const int*   ei    = (const int*)d_in[1];
    const int*   src   = ei;
    const int*   dst   = ei + E_REAL;
    const int*   et    = (const int*)d_in[2];
    const int*   batch = (const int*)d_in[3];
    const float* W1    = (const float*)d_in[4];
    const float* root1 = (const float*)d_in[5];
    const float* b1    = (const float*)d_in[6];
    const float* W2    = (const float*)d_in[7];
    const float* root2 = (const float*)d_in[8];
    const float* b2    = (const float*)d_in[9];
    const float* wsw   = (const float*)d_in[10];
    const float* wsb   = (const float*)d_in[11];
    const float* m1w   = (const float*)d_in[12];
    const float* m1b   = (const float*)d_in[13];
    const float* m2w   = (const float*)d_in[14];
    const float* m2b   = (const float*)d_in[15];
    const float* m3w   = (const float*)d_in[16];
    const float* m3b   = (const float*)d_in[17];
    const float* ow    = (const float*)d_in[18];
    const float* ob    = (const float*)d_in[19];

    char* ws = (char*)d_ws;
    size_t off = 0;
    auto alloc = [&](size_t bytes) {
        void* p = ws + off;
        off = (off + bytes + 255) & ~(size_t)255;
        return p;
    };
    // common buffers
    int*   cnt       = (int*)alloc((size_t)N_NODES * NREL * 4);     // 13.0 MB
    int*   blockHist = (int*)alloc((size_t)TOT_HIST * 4);
    int*   baseArr   = (int*)alloc((size_t)TOT_HIST * 4);
    int*   perm      = (int*)alloc((size_t)E_REAL * 4);             // 0.8 MB
    int*   srcOf     = (int*)alloc((size_t)E_REAL * 4);             // 0.8 MB
    float* wOf       = (float*)alloc((size_t)E_REAL * 4);           // 0.8 MB
    int*   relStartA = (int*)alloc(NREL * 4);
    int*   relTotA   = (int*)alloc(NREL * 4);
    int*   pbStartA  = (int*)alloc(NREL * 4);
    int*   relOfBlk  = (int*)alloc(MAX_PB * 4);
    int*   npb       = (int*)alloc(4);
    int*   psumA     = (int*)alloc(64 * 4);
    int*   psumB     = (int*)alloc(64 * 4);
    unsigned short* xb  = (unsigned short*)alloc((size_t)N_NODES * 128 * 2);    // 12.8 MB
    unsigned short* w1b = (unsigned short*)alloc((size_t)NREL * 256 * 128 * 2); // 4.3 MB
    unsigned short* w2b = (unsigned short*)alloc((size_t)NREL * 256 * 256 * 2); // 8.5 MB
    unsigned short* r1b = (unsigned short*)alloc((size_t)256 * 128 * 2);
    unsigned short* r2b = (unsigned short*)alloc((size_t)256 * 256 * 2);
    unsigned short* h1b = (unsigned short*)alloc((size_t)N_NODES * HDIM * 2);   // 25.6 MB
    float* emb = (float*)alloc((size_t)NGRAPH * HDIM * 4);                       // 1.6 MB
    size_t off_common = off;

    // fast-path extras
    unsigned short* hinit = (unsigned short*)alloc((size_t)N_NODES * HDIM * 2); // 25.6 MB
    unsigned short* msg   = (unsigned short*)alloc((size_t)E_REAL * HDIM * 2);  // 102.4 MB
    int* qofp    = (int*)alloc((size_t)E_REAL * 4);
    int* cntD    = (int*)alloc((size_t)N_NODES * 4);
    int* startD  = (int*)alloc((size_t)N_NODES * 4);
    int* cursorD = (int*)alloc((size_t)N_NODES * 4);
    size_t need_fast = off;

    float* hf = nullptr;
    bool fast = (ws_size >= need_fast);
    if (!fast) {
        off = off_common;
        hf = (float*)alloc((size_t)N_NODES * HDIM * 4);  // 51.2 MB
        char* hh = (char*)hf;   // dst structures alias hf (used before hf written)
        qofp    = (int*)hh;                                 hh += (size_t)E_REAL * 4;
        cntD    = (int*)hh;                                 hh += (size_t)N_NODES * 4;
        startD  = (int*)hh;                                 hh += (size_t)N_NODES * 4;
        cursorD = (int*)hh;
        hinit = h1b;  // unused sink
        msg = h1b;    // unused sink
    }

    hipMemsetAsync(cnt, 0, (size_t)N_NODES * NREL * 4, stream);
    hipMemsetAsync(cntD, 0, (size_t)N_NODES * 4, stream);

    count_kernel<<<NB_CNT, 256, 0, stream>>>(src, dst, et, cnt, blockHist, cntD);
    scan_part2<<<NSA + NSB, 1024, 0, stream>>>(blockHist, cntD, psumA, psumB);
    scan_apply2<<<NSA + NSB, 1024, 0, stream>>>(blockHist, cntD, psumA, psumB,
                                                baseArr, startD, cursorD);
    meta_kernel<<<1, 1024, 0, stream>>>(baseArr, relStartA, relTotA, pbStartA, relOfBlk, npb);
    scatter_sorted<<<NB_R, 256, 0, stream>>>(src, dst, et, baseArr, cnt,
                                             perm, cursorD, qofp, srcOf, wOf);

    cvt_all<<<(CVT_TOT + 255) / 256, 256, 0, stream>>>(x, W1, W2, root1, root2,
                                                       xb, w1b, w2b, r1b, r2b);

    if (fast) {
        // layer 1
        init_gemm<128><<<GRID_I, 256, 0, stream>>>(xb, r1b, w1b, b1, hinit, cnt);
        edge_msg<128><<<MAX_PB, 256, 0, stream>>>(xb, w1b, msg,
            srcOf, wOf, qofp, relOfBlk, pbStartA, relStartA, relTotA, npb);
        reduce_kernel<<<(N_NODES + 7) / 8, 256, 0, stream>>>(hinit, msg, startD, cntD, h1b);
        // layer 2: reduce fused with pooling, h2 never materialized
        init_gemm<256><<<GRID_I, 256, 0, stream>>>(h1b, r2b, w2b, b2, hinit, cnt);
        edge_msg<256><<<MAX_PB, 256, 0, stream>>>(h1b, w2b, msg,
            srcOf, wOf, qofp, relOfBlk, pbStartA, relStartA, relTotA, npb);
        reduce_pool<<<NGRAPH, 256, 0, stream>>>(hinit, msg, startD, cntD,
                                                batch, wsw, wsb, emb);
    } else {
        hipMemsetAsync(emb, 0, (size_t)NGRAPH * HDIM * 4, stream);
        mfma_gemm<128, 0><<<GRID_I, 256, 0, stream>>>(xb, r1b, w1b, b1, hf,
            nullptr, nullptr, nullptr, cnt, nullptr, nullptr, nullptr, nullptr, nullptr);
        mfma_gemm<128, 1><<<MAX_PB, 256, 0, stream>>>(xb, w1b, nullptr, nullptr, hf,
            perm, src, dst, cnt, relOfBlk, pbStartA, relStartA, relTotA, npb);
        cvt_rows<<<(N_NODES * HDIM / 8 + 255) / 256, 256, 0, stream>>>(hf, h1b, N_NODES * HDIM / 8, 1);
        mfma_gemm<256, 0><<<GRID_I, 256, 0, stream>>>(h1b, r2b, w2b, b2, hf,
            nullptr, nullptr, nullptr, cnt, nullptr, nullptr, nullptr, nullptr, nullptr);
        mfma_gemm<256, 1><<<MAX_PB, 256, 0, stream>>>(h1b, w2b, nullptr, nullptr, hf,
            perm, src, dst, cnt, relOfBlk, pbStartA, relStartA, relTotA, npb);
        pool_kernel<<<N_NODES, 256, 0, stream>>>(hf, batch, wsw, wsb, emb);
    }
    mlp_kernel<<<NGRAPH, 64, 0, stream>>>(emb, m1w, m1b, m2w, m2b, m3w, m3b, ow, ob, (float*)d_out);
}

// Round 19
// 327.240 us; speedup vs baseline: 1.0053x; 1.0053x over previous
//
#include <hip/hip_runtime.h>
#include <math.h>

#define N_NODES 50000
#define E_REAL  200000
#define E_MEAN  250000   // real + self-loops (self handled densely in init)
#define NREL    65
#define HDIM    256
#define NGRAPH  1600
#define NB_R    ((E_REAL + 255) / 256)   // 782 blocks over REAL edges
#define NB_CNT  ((E_MEAN + 255) / 256)   // 977 blocks to also count self-loops
#define TOT_HIST (NREL * NB_R)           // 50830
#define MB      64                        // rows per MFMA tile
#define MAX_PB  3264                      // >= 65 + E_REAL/64 = 3190; divisible by 8
#define GRID_I  ((N_NODES + MB - 1) / MB) // 782 init tiles
#define NSA     ((TOT_HIST + 1023) / 1024)  // 50 scan blocks (region A)
#define NSB     ((N_NODES + 1023) / 1024)   // 49 scan blocks (region B)

typedef __attribute__((ext_vector_type(8))) short short8;   // 8 bf16 (4 VGPRs)
typedef __attribute__((ext_vector_type(4))) float floatx4;  // MFMA C/D frag
typedef const __attribute__((address_space(1))) void GPtr;
typedef __attribute__((address_space(3))) void LPtr;

__device__ __forceinline__ unsigned short f2bf(float f) {
    unsigned int u = __float_as_uint(f);
    unsigned int r = u + 0x7FFFu + ((u >> 16) & 1u);  // RNE
    return (unsigned short)(r >> 16);
}
__device__ __forceinline__ float bf2f(unsigned short u) {
    return __uint_as_float(((unsigned int)u) << 16);
}

// async global->LDS, 16B per lane; LDS dest must be wave-uniform base + lane*16
__device__ __forceinline__ void gl_lds16(const unsigned short* g, unsigned short* l) {
    __builtin_amdgcn_global_load_lds((GPtr*)g,
        (LPtr*)(unsigned int)(unsigned long long)(void*)l, 16, 0, 0);
}

// counts: cnt[d][r] over ALL edges (incl self, rel 0); blockHist/cntD over REAL only
__global__ void count_kernel(const int* __restrict__ src, const int* __restrict__ dst,
                             const int* __restrict__ et, int* __restrict__ cnt,
                             int* __restrict__ blockHist, int* __restrict__ cntD) {
    __shared__ int lhist[NREL];
    int t = threadIdx.x;
    if (t < NREL) lhist[t] = 0;
    __syncthreads();
    int e = blockIdx.x * 256 + t;
    if (e < E_REAL) {
        int d = dst[e], r = et[e];
        atomicAdd(&cnt[d * NREL + r], 1);
        atomicAdd(&cntD[d], 1);
        atomicAdd(&lhist[r], 1);
    } else if (e < E_MEAN) {
        atomicAdd(&cnt[(e - E_REAL) * NREL], 1);   // self-loop, rel 0
    }
    __syncthreads();
    if (t < NREL && blockIdx.x < NB_R) blockHist[t * NB_R + blockIdx.x] = lhist[t];
}

// combined hierarchical scan, phase 1
__global__ void scan_part2(const int* __restrict__ inA, const int* __restrict__ inB,
                           int* __restrict__ psumA, int* __restrict__ psumB) {
    __shared__ int red[1024];
    int t = threadIdx.x;
    int b = blockIdx.x;
    const int* in; int n; int bi;
    if (b < NSA) { in = inA; n = TOT_HIST; bi = b; }
    else         { in = inB; n = N_NODES;  bi = b - NSA; }
    int g = bi * 1024 + t;
    red[t] = (g < n) ? in[g] : 0;
    __syncthreads();
    for (int off = 512; off >= 1; off >>= 1) {
        if (t < off) red[t] += red[t + off];
        __syncthreads();
    }
    if (t == 0) {
        if (b < NSA) psumA[bi] = red[0];
        else         psumB[bi] = red[0];
    }
}

// combined phase 2: exclusive scan both regions; B region also fills out2 (cursor)
__global__ void scan_apply2(const int* __restrict__ inA, const int* __restrict__ inB,
                            const int* __restrict__ psumA, const int* __restrict__ psumB,
                            int* __restrict__ outA, int* __restrict__ outB,
                            int* __restrict__ outB2) {
    __shared__ int sums[1024];
    __shared__ int soff;
    int t = threadIdx.x;
    int b = blockIdx.x;
    const int* in; const int* ps; int n; int bi;
    if (b < NSA) { in = inA; ps = psumA; n = TOT_HIST; bi = b; }
    else         { in = inB; ps = psumB; n = N_NODES;  bi = b - NSA; }
    if (t < 64) {
        int v = (t < bi) ? ps[t] : 0;
        for (int off = 32; off >= 1; off >>= 1) v += __shfl_down(v, off, 64);
        if (t == 0) soff = v;
    }
    int g = bi * 1024 + t;
    int v = (g < n) ? in[g] : 0;
    sums[t] = v;
    __syncthreads();
    for (int off = 1; off < 1024; off <<= 1) {
        int u = (t >= off) ? sums[t - off] : 0;
        __syncthreads();
        sums[t] += u;
        __syncthreads();
    }
    if (g < n) {
        int excl = soff + sums[t] - v;
        if (b < NSA) outA[g] = excl;
        else { outB[g] = excl; outB2[g] = excl; }
    }
}

// relation segment metadata (64-granule tiles)
__global__ void meta_kernel(const int* __restrict__ baseArr,
                            int* __restrict__ relStart, int* __restrict__ relTot,
                            int* __restrict__ pBlockStart, int* __restrict__ relOfBlock,
                            int* __restrict__ npb) {
    __shared__ int sStart[NREL + 1];
    __shared__ int sPB[NREL + 1];
    int t = threadIdx.x;
    if (t < NREL) sStart[t] = baseArr[t * NB_R];
    if (t == 0) sStart[NREL] = E_REAL;
    __syncthreads();
    if (t < NREL) {
        relStart[t] = sStart[t];
        relTot[t] = sStart[t + 1] - sStart[t];
    }
    if (t == 0) {
        int a2 = 0;
        for (int r = 0; r < NREL; ++r) {
            sPB[r] = a2;
            int tot = sStart[r + 1] - sStart[r];
            a2 += (tot + MB - 1) / MB;
        }
        sPB[NREL] = a2;
        npb[0] = a2;
    }
    __syncthreads();
    if (t < NREL) pBlockStart[t] = sPB[t];
    int NPB = sPB[NREL];
    for (int b = t; b < NPB; b += 1024) {
        int lo = 0, hi = NREL - 1;
        while (lo < hi) { int mid = (lo + hi + 1) >> 1; if (sPB[mid] <= b) lo = mid; else hi = mid - 1; }
        relOfBlock[b] = lo;
    }
}

// counting-sort scatter by relation (REAL edges). Besides perm/qofp, precompute
// per-slot edge metadata (srcOf, wOf) so the edge GEMM's meta phase is three
// coalesced loads with no dependent random-load chain (cnt is complete here).
__global__ void scatter_sorted(const int* __restrict__ src, const int* __restrict__ dst,
                               const int* __restrict__ et, const int* __restrict__ base,
                               const int* __restrict__ cnt,
                               int* __restrict__ perm, int* __restrict__ cursorD,
                               int* __restrict__ qofp, int* __restrict__ srcOf,
                               float* __restrict__ wOf) {
    __shared__ int lhist[NREL];
    int t = threadIdx.x;
    int b = blockIdx.x;
    if (t < NREL) lhist[t] = 0;
    __syncthreads();
    int e = b * 256 + t;
    if (e < E_REAL) {
        int d = dst[e], r = et[e];
        int local = atomicAdd(&lhist[r], 1);
        int p = base[r * NB_R + b] + local;
        perm[p] = e;
        int q = atomicAdd(&cursorD[d], 1);
        qofp[p] = q;
        srcOf[p] = src[e];
        wOf[p] = 1.0f / (float)cnt[d * NREL + r];
    }
}

// --- conversion helpers (device) ---
__device__ __forceinline__ void cvt_row_chunk(const float* __restrict__ in,
                                              unsigned short* __restrict__ out,
                                              int i, int relu) {
    const float4* p = (const float4*)in + (size_t)i * 2;
    float4 a = p[0], b = p[1];
    float v[8] = {a.x, a.y, a.z, a.w, b.x, b.y, b.z, b.w};
    short8 o;
#pragma unroll
    for (int j = 0; j < 8; ++j) {
        float f = relu ? fmaxf(v[j], 0.f) : v[j];
        o[j] = (short)f2bf(f);
    }
    ((short8*)out)[i] = o;
}
__device__ __forceinline__ void cvt_wT_chunk(const float* __restrict__ W,
                                             unsigned short* __restrict__ out,
                                             int i, int K, int N) {
    int kc8 = K / 8;
    int kc = i % kc8;
    int tmp = i / kc8;
    int n = tmp % N;
    int r = tmp / N;
    const float* src = W + ((size_t)r * K + kc * 8) * N + n;
    short8 o;
#pragma unroll
    for (int j = 0; j < 8; ++j) o[j] = (short)f2bf(src[(size_t)j * N]);
    ((short8*)out)[i] = o;
}

// fp32 row-major -> bf16 row-major, optional relu (standalone, fallback path)
__global__ void cvt_rows(const float* __restrict__ in, unsigned short* __restrict__ out,
                         int nchunk, int relu) {
    int i = blockIdx.x * 256 + threadIdx.x;
    if (i >= nchunk) return;
    cvt_row_chunk(in, out, i, relu);
}

// all five conversions in one dispatch
#define CVT_NX  (N_NODES * 128 / 8)          // 800000
#define CVT_W1  (NREL * 256 * 16)            // 266240
#define CVT_W2  (NREL * 256 * 32)            // 532480
#define CVT_R1  (256 * 16)                   // 4096
#define CVT_R2  (256 * 32)                   // 8192
#define CVT_TOT (CVT_NX + CVT_W1 + CVT_W2 + CVT_R1 + CVT_R2)
__global__ void cvt_all(const float* __restrict__ x, const float* __restrict__ W1,
                        const float* __restrict__ W2, const float* __restrict__ root1,
                        const float* __restrict__ root2,
                        unsigned short* __restrict__ xb, unsigned short* __restrict__ w1b,
                        unsigned short* __restrict__ w2b, unsigned short* __restrict__ r1b,
                        unsigned short* __restrict__ r2b) {
    int i = blockIdx.x * 256 + threadIdx.x;
    if (i < CVT_NX) { cvt_row_chunk(x, xb, i, 0); return; }
    i -= CVT_NX;
    if (i < CVT_W1) { cvt_wT_chunk(W1, w1b, i, 128, 256); return; }
    i -= CVT_W1;
    if (i < CVT_W2) { cvt_wT_chunk(W2, w2b, i, 256, 256); return; }
    i -= CVT_W2;
    if (i < CVT_R1) { cvt_wT_chunk(root1, r1b, i, 128, 256); return; }
    i -= CVT_R1;
    if (i < CVT_R2) { cvt_wT_chunk(root2, r2b, i, 256, 256); return; }
}

// B-ring warm-up at a K-offset
template<int K>
__device__ __forceinline__ void ring_init_off(const unsigned short* __restrict__ Bp,
                                              int koff, int lrow, int lk,
                                              short8 (&b0)[4], short8 (&b1)[4]) {
#pragma unroll
    for (int nf = 0; nf < 4; ++nf)
        b0[nf] = *(const short8*)(Bp + (size_t)(nf * 16 + lrow) * K + koff + lk * 8);
#pragma unroll
    for (int nf = 0; nf < 4; ++nf)
        b1[nf] = *(const short8*)(Bp + (size_t)(nf * 16 + lrow) * K + koff + 32 + lk * 8);
}

// full-tile K-sweep with pre-loaded ring (row stride K)
template<int K>
__device__ __forceinline__ void gemm_main(const unsigned short* __restrict__ Bp,
                                          const unsigned short* lds,
                                          int lrow, int lk,
                                          short8 (&b0)[4], short8 (&b1)[4],
                                          floatx4 (&acc)[4][4]) {
    constexpr int KS = K / 32;
    short8 bb[3][4];
#pragma unroll
    for (int nf = 0; nf < 4; ++nf) { bb[0][nf] = b0[nf]; bb[1][nf] = b1[nf]; }
#pragma unroll
    for (int ks = 0; ks < KS; ++ks) {
        short8 a[4];
#pragma unroll
        for (int mf = 0; mf < 4; ++mf) {
            int row = mf * 16 + lrow;
            int c = (ks * 4 + lk) ^ (row & 7);
            a[mf] = *(const short8*)((const char*)lds + row * (K * 2) + c * 16);
        }
        if (ks + 2 < KS) {
#pragma unroll
            for (int nf = 0; nf < 4; ++nf)
                bb[(ks + 2) % 3][nf] = *(const short8*)(Bp + (size_t)(nf * 16 + lrow) * K + (ks + 2) * 32 + lk * 8);
        }
#pragma unroll
        for (int mf = 0; mf < 4; ++mf)
#pragma unroll
            for (int nf = 0; nf < 4; ++nf)
                acc[mf][nf] = __builtin_amdgcn_mfma_f32_16x16x32_bf16(a[mf], bb[ks % 3][nf], acc[mf][nf], 0, 0, 0);
    }
}

// classic one-call K-sweep (ring loaded inline)
template<int K>
__device__ __forceinline__ void gemm_pass(const unsigned short* __restrict__ Bp,
                                          const unsigned short* lds,
                                          int lrow, int lk, floatx4 (&acc)[4][4]) {
    short8 b0[4], b1[4];
    ring_init_off<K>(Bp, 0, lrow, lk, b0, b1);
    gemm_main<K>(Bp, lds, lrow, lk, b0, b1, acc);
}

// half-tile K-sweep: KH = K/64 K-steps from a compact half buffer (row stride K/2)
template<int K>
__device__ __forceinline__ void gemm_half(const unsigned short* __restrict__ Bp,
                                          int koff, const unsigned short* buf,
                                          int lrow, int lk,
                                          short8 (&b0)[4], short8 (&b1)[4],
                                          floatx4 (&acc)[4][4]) {
    constexpr int KH = K / 64;       // K-steps per half
    constexpr int CH2 = K / 16;      // 16B chunks per row per half
    short8 bb[3][4];
#pragma unroll
    for (int nf = 0; nf < 4; ++nf) { bb[0][nf] = b0[nf]; bb[1][nf] = b1[nf]; }
#pragma unroll
    for (int ks2 = 0; ks2 < KH; ++ks2) {
        short8 a[4];
#pragma unroll
        for (int mf = 0; mf < 4; ++mf) {
            int row = mf * 16 + lrow;
            int c = (ks2 * 4 + lk) ^ (row & 7);
            a[mf] = *(const short8*)(buf + (row * CH2 + c) * 8);
        }
        if (ks2 + 2 < KH) {
#pragma unroll
            for (int nf = 0; nf < 4; ++nf)
                bb[(ks2 + 2) % 3][nf] = *(const short8*)(Bp + (size_t)(nf * 16 + lrow) * K + koff + (ks2 + 2) * 32 + lk * 8);
        }
#pragma unroll
        for (int mf = 0; mf < 4; ++mf)
#pragma unroll
            for (int nf = 0; nf < 4; ++nf)
                acc[mf][nf] = __builtin_amdgcn_mfma_f32_16x16x32_bf16(a[mf], bb[ks2 % 3][nf], acc[mf][nf], 0, 0, 0);
    }
}

// stage one K-half of the A tile (compact: row stride K/2), inverse-swizzled source
template<int K>
__device__ __forceinline__ void stage_half(const unsigned short* __restrict__ A,
                                           unsigned short* buf, const int* ssrc,
                                           int h, int t) {
    constexpr int CH2 = K / 16;
#pragma unroll
    for (int i = 0; i < (MB * CH2) / 256; ++i) {
        int q = i * 256 + t;
        int row = q / CH2, sl = q % CH2;
        int cg = h * CH2 + (sl ^ (row & 7));
        gl_lds16(A + (size_t)ssrc[row] * K + cg * 8, buf + q * 8);
    }
}

// async full-tile A-staging
template<int K, bool EDGE>
__device__ __forceinline__ void stage_A(const unsigned short* __restrict__ A,
                                        unsigned short* lds, const int* ssrc,
                                        int rowbase, int t) {
    constexpr int CH = K / 8;
#pragma unroll
    for (int i = 0; i < (MB * CH) / 256; ++i) {
        int q = i * 256 + t;
        int row = q / CH, sl = q % CH;
        int srow;
        if constexpr (EDGE) srow = ssrc[row];
        else { srow = rowbase + row; if (srow >= N_NODES) srow = N_NODES - 1; }
        int cg = sl ^ (row & 7);
        gl_lds16(A + (size_t)srow * K + cg * 8, lds + q * 8);
    }
}

// EDGE message GEMM. K=256: split-K half-staged pipeline (constant 32KB LDS).
// K=128: full-tile. XCD-chunked block swizzle. Meta phase = 3 coalesced loads
// (srcOf/qofp/wOf precomputed in scatter_sorted), staged in LDS (r16-proven).
template<int K>
__global__ __launch_bounds__(256) void edge_msg(
    const unsigned short* __restrict__ A,   // [*][K] bf16 rows
    const unsigned short* __restrict__ B,   // [R][256][K] bf16 (transposed)
    unsigned short* __restrict__ outB,      // msg rows
    const int* __restrict__ srcOf, const float* __restrict__ wOf,
    const int* __restrict__ qofp,
    const int* __restrict__ relOfBlock, const int* __restrict__ pBlockStart,
    const int* __restrict__ relStart, const int* __restrict__ relTot,
    const int* __restrict__ npb)
{
    __shared__ __align__(16) unsigned short lds[MB * HDIM];  // stage + pack (aliased)
    __shared__ int ssrc[MB];
    __shared__ int sqd[MB];
    __shared__ float sw[MB];
    int t = threadIdx.x;
    // XCD-chunked bijective swizzle (MAX_PB % 8 == 0)
    int b = (blockIdx.x & 7) * (MAX_PB / 8) + (blockIdx.x >> 3);
    if (b >= npb[0]) return;
    int rel = relOfBlock[b];
    int jb = b - pBlockStart[rel];
    int rs = relStart[rel];
    int nval = relTot[rel] - jb * MB; if (nval > MB) nval = MB;
    if (t < MB) {
        int s = 0, qd = 0; float w = 0.f;
        if (t < nval) {
            int p = rs + jb * MB + t;
            s = srcOf[p];       // coalesced, independent
            qd = qofp[p];       // coalesced, independent
            w = wOf[p];         // coalesced, independent
        }
        ssrc[t] = s; sqd[t] = qd; sw[t] = w;
    }
    __syncthreads();

    int wave = t >> 6, lane = t & 63;
    int n0 = wave * 64;
    int lrow = lane & 15, lk = lane >> 4;
    const unsigned short* Bp = B + ((size_t)rel * HDIM + n0) * K;

    floatx4 acc[4][4];
#pragma unroll
    for (int mf = 0; mf < 4; ++mf)
#pragma unroll
        for (int nf = 0; nf < 4; ++nf) acc[mf][nf] = (floatx4)0.f;

    if constexpr (K == 256) {
        constexpr int CH2 = K / 16;
        constexpr int HELEM = MB * CH2 * 8;
        unsigned short* buf0 = lds;
        unsigned short* buf1 = lds + HELEM;
        stage_half<K>(A, buf0, ssrc, 0, t);
        short8 b0[4], b1[4];
        ring_init_off<K>(Bp, 0, lrow, lk, b0, b1);   // overlaps the half0 drain
        __syncthreads();                              // drains half0
        stage_half<K>(A, buf1, ssrc, 1, t);           // async: hides under phase 0
        gemm_half<K>(Bp, 0, buf0, lrow, lk, b0, b1, acc);      // phase 0
        ring_init_off<K>(Bp, K / 2, lrow, lk, b0, b1);         // phase-1 ring under drain
        __syncthreads();                              // drains half1 (mostly covered)
        gemm_half<K>(Bp, K / 2, buf1, lrow, lk, b0, b1, acc);  // phase 1
    } else {
        stage_A<K, true>(A, lds, ssrc, 0, t);
        short8 b0[4], b1[4];
        ring_init_off<K>(Bp, 0, lrow, lk, b0, b1);   // overlaps the staging drain
        __syncthreads();
        gemm_main<K>(Bp, lds, lrow, lk, b0, b1, acc);
    }

    __syncthreads();  // all A reads done; reuse lds as pack
#pragma unroll
    for (int mf = 0; mf < 4; ++mf) {
        int mbase = mf * 16 + lk * 4;
#pragma unroll
        for (int i = 0; i < 4; ++i) {
            int row = mbase + i;
            float w = sw[row];
#pragma unroll
            for (int nf = 0; nf < 4; ++nf)
                lds[row * HDIM + n0 + nf * 16 + lrow] = f2bf(acc[mf][nf][i] * w);
        }
    }
    __syncthreads();
    for (int q = t; q < nval * 32; q += 256) {
        int row = q >> 5, c = q & 31;
        *(uint4*)(outB + (size_t)sqd[row] * HDIM + c * 8) = *(const uint4*)(lds + row * HDIM + c * 8);
    }
}

// INIT dense GEMM: hinit = bf16( A@root + bias + (A@W0)*(1/cnt[d,0]) )
template<int K>
__global__ __launch_bounds__(256) void init_gemm(
    const unsigned short* __restrict__ A,
    const unsigned short* __restrict__ Broot,  // [256][K] root panel
    const unsigned short* __restrict__ Bself,  // W[0] panel
    const float* __restrict__ bias,
    unsigned short* __restrict__ outB,
    const int* __restrict__ cnt)
{
    __shared__ __align__(16) unsigned short lds[MB * HDIM];
    __shared__ float sw[MB];
    int t = threadIdx.x;
    int rowbase = blockIdx.x * MB;
    if (t < MB) {
        int srow = rowbase + t; if (srow >= N_NODES) srow = N_NODES - 1;
        sw[t] = 1.0f / (float)cnt[srow * NREL];   // 1/cnt[d,0] for self term
    }
    int wave = t >> 6, lane = t & 63;
    int n0 = wave * 64;
    int lrow = lane & 15, lk = lane >> 4;

    stage_A<K, false>(A, lds, nullptr, rowbase, t);
    short8 b0[4], b1[4];
    ring_init_off<K>(Bself + (size_t)n0 * K, 0, lrow, lk, b0, b1);  // overlaps drain
    __syncthreads();

    floatx4 acc[4][4];
#pragma unroll
    for (int mf = 0; mf < 4; ++mf)
#pragma unroll
        for (int nf = 0; nf < 4; ++nf) acc[mf][nf] = (floatx4)0.f;
    // pass 1: self W0; scale per-row; pass 2: root into same acc
    gemm_main<K>(Bself + (size_t)n0 * K, lds, lrow, lk, b0, b1, acc);
#pragma unroll
    for (int mf = 0; mf < 4; ++mf) {
        int mbase = mf * 16 + lk * 4;
#pragma unroll
        for (int i = 0; i < 4; ++i) {
            float w = sw[mbase + i];
#pragma unroll
            for (int nf = 0; nf < 4; ++nf) acc[mf][nf][i] *= w;
        }
    }
    gemm_pass<K>(Broot + (size_t)n0 * K, lds, lrow, lk, acc);

    float bv[4];
#pragma unroll
    for (int nf = 0; nf < 4; ++nf) bv[nf] = bias[n0 + nf * 16 + lrow];
    __syncthreads();  // A reads done; reuse lds as pack
#pragma unroll
    for (int mf = 0; mf < 4; ++mf) {
        int mbase = mf * 16 + lk * 4;
#pragma unroll
        for (int i = 0; i < 4; ++i) {
            int row = mbase + i;
#pragma unroll
            for (int nf = 0; nf < 4; ++nf)
                lds[row * HDIM + n0 + nf * 16 + lrow] = f2bf(acc[mf][nf][i] + bv[nf]);
        }
    }
    __syncthreads();
    int limit = N_NODES - rowbase; if (limit > MB) limit = MB;
    for (int q = t; q < limit * 32; q += 256) {
        int row = q >> 5, c = q & 31;
        *(uint4*)(outB + ((size_t)rowbase + row) * HDIM + c * 8) = *(const uint4*)(lds + row * HDIM + c * 8);
    }
}

// fallback MFMA GEMM (round-3 proven path)
template<int K, int MODE>
__global__ __launch_bounds__(256) void mfma_gemm(
    const unsigned short* __restrict__ A,
    const unsigned short* __restrict__ B,
    const unsigned short* __restrict__ Bself,
    const float* __restrict__ bias,
    float* __restrict__ outF,
    const int* __restrict__ perm, const int* __restrict__ srcA,
    const int* __restrict__ dstA, const int* __restrict__ cnt,
    const int* __restrict__ relOfBlock, const int* __restrict__ pBlockStart,
    const int* __restrict__ relStart, const int* __restrict__ relTot,
    const int* __restrict__ npb)
{
    constexpr bool EDGE = (MODE == 1);
    __shared__ __align__(16) unsigned short lds[MB * HDIM];
    __shared__ int ssrc[MB];
    __shared__ int sdst[MB];
    __shared__ float sw[MB];
    int t = threadIdx.x;
    int b = blockIdx.x;
    int rel = 0, rowbase = 0, jb = 0, rs = 0, nval = MB;
    if constexpr (EDGE) {
        if (b >= npb[0]) return;
        rel = relOfBlock[b];
        jb = b - pBlockStart[rel];
        rs = relStart[rel];
        nval = relTot[rel] - jb * MB; if (nval > MB) nval = MB;
        if (t < MB) {
            int s = 0, d = 0; float w = 0.f;
            if (t < nval) {
                int p = rs + jb * MB + t;
                int e = perm[p];
                s = srcA[e]; d = dstA[e];
                w = 1.0f / (float)cnt[d * NREL + rel];
            }
            ssrc[t] = s; sdst[t] = d; sw[t] = w;
        }
        __syncthreads();
    } else {
        rowbase = b * MB;
        if (t < MB) {
            int srow = rowbase + t; if (srow >= N_NODES) srow = N_NODES - 1;
            sw[t] = 1.0f / (float)cnt[srow * NREL];
        }
    }
    stage_A<K, EDGE>(A, lds, ssrc, rowbase, t);
    __syncthreads();

    int wave = t >> 6, lane = t & 63;
    int n0 = wave * 64;
    int lrow = lane & 15;
    int lk = lane >> 4;
    floatx4 acc[4][4];
#pragma unroll
    for (int mf = 0; mf < 4; ++mf)
#pragma unroll
        for (int nf = 0; nf < 4; ++nf) acc[mf][nf] = (floatx4)0.f;

    if constexpr (EDGE) {
        gemm_pass<K>(B + ((size_t)rel * HDIM + n0) * K, lds, lrow, lk, acc);
    } else {
        gemm_pass<K>(Bself + (size_t)n0 * K, lds, lrow, lk, acc);
#pragma unroll
        for (int mf = 0; mf < 4; ++mf) {
            int mbase = mf * 16 + lk * 4;
#pragma unroll
            for (int i = 0; i < 4; ++i) {
                float w = sw[mbase + i];
#pragma unroll
                for (int nf = 0; nf < 4; ++nf) acc[mf][nf][i] *= w;
            }
        }
        gemm_pass<K>(B + (size_t)n0 * K, lds, lrow, lk, acc);
    }

    if constexpr (MODE == 1) {
#pragma unroll
        for (int mf = 0; mf < 4; ++mf) {
            int mbase = mf * 16 + lk * 4;
#pragma unroll
            for (int i = 0; i < 4; ++i) {
                int mm = mbase + i;
                float w = sw[mm];
                if (w != 0.f) {
                    int drow = sdst[mm];
#pragma unroll
                    for (int nf = 0; nf < 4; ++nf) {
                        int col = n0 + nf * 16 + lrow;
                        atomicAdd(&outF[(size_t)drow * HDIM + col], acc[mf][nf][i] * w);
                    }
                }
            }
        }
    } else {
        float bv[4];
#pragma unroll
        for (int nf = 0; nf < 4; ++nf) bv[nf] = bias[n0 + nf * 16 + lrow];
#pragma unroll
        for (int mf = 0; mf < 4; ++mf) {
            int mbase = mf * 16 + lk * 4;
#pragma unroll
            for (int i = 0; i < 4; ++i) {
                int mm = rowbase + mbase + i;
                if (mm < N_NODES) {
#pragma unroll
                    for (int nf = 0; nf < 4; ++nf) {
                        int col = n0 + nf * 16 + lrow;
                        outF[(size_t)mm * HDIM + col] = acc[mf][nf][i] + bv[nf];
                    }
                }
            }
        }
    }
}

// layer-1 gather-reduce: msg rows for dst d are CONTIGUOUS [startD[d], +cntD[d]).
// 16B/lane: 32 lanes per dst (row = 512B = 32 x 16B), 8 dsts per block.
__global__ __launch_bounds__(256) void reduce_kernel(
    const unsigned short* __restrict__ hinit, const unsigned short* __restrict__ msg,
    const int* __restrict__ startD, const int* __restrict__ cntD,
    unsigned short* __restrict__ hout)
{
    int t = threadIdx.x;
    int lane = t & 63;
    int d = blockIdx.x * 8 + ((t >> 6) << 1) + (lane >> 5);
    if (d >= N_NODES) return;
    int sl = lane & 31;
    int s0 = startD[d], n = cntD[d];
    short8 hv = *(const short8*)(hinit + (size_t)d * HDIM + sl * 8);
    float v[8];
#pragma unroll
    for (int j = 0; j < 8; ++j) v[j] = bf2f((unsigned short)hv[j]);
    const unsigned short* mp = msg + (size_t)s0 * HDIM + sl * 8;
#pragma unroll 4
    for (int q = 0; q < n; ++q) {
        short8 m = *(const short8*)(mp + (size_t)q * HDIM);
#pragma unroll
        for (int j = 0; j < 8; ++j) v[j] += bf2f((unsigned short)m[j]);
    }
    short8 o;
#pragma unroll
    for (int j = 0; j < 8; ++j) o[j] = (short)f2bf(fmaxf(v[j], 0.f));
    *(short8*)(hout + (size_t)d * HDIM + sl * 8) = o;
}

// FUSED layer-2 reduce + weighted-sum pooling (atomic-free; h2 never materialized)
__global__ __launch_bounds__(256) void reduce_pool(
    const unsigned short* __restrict__ hinit, const unsigned short* __restrict__ msg,
    const int* __restrict__ startD, const int* __restrict__ cntD,
    const int* __restrict__ batch, const float* __restrict__ wsw,
    const float* __restrict__ wsb, float* __restrict__ emb)
{
    int g = blockIdx.x;
    int t = threadIdx.x;
    __shared__ int slo, shi;
    __shared__ float sacc[4][HDIM];
    if (t == 0) {
        int lo = 0, hi = N_NODES;
        while (lo < hi) { int m = (lo + hi) >> 1; if (batch[m] < g) lo = m + 1; else hi = m; }
        slo = lo;
        int lo2 = lo, hi2 = N_NODES;
        while (lo2 < hi2) { int m = (lo2 + hi2) >> 1; if (batch[m] < g + 1) lo2 = m + 1; else hi2 = m; }
        shi = lo2;
    }
    __syncthreads();
    int wave = t >> 6, lane = t & 63;
    float4 wv = *(const float4*)(wsw + lane * 4);
    float wb = wsb[0];
    float a0 = 0.f, a1 = 0.f, a2 = 0.f, a3 = 0.f;
    for (int d = slo + wave; d < shi; d += 4) {
        int s0 = startD[d], n = cntD[d];
        ushort4 hv = *(const ushort4*)(hinit + (size_t)d * HDIM + lane * 4);
        float v0 = bf2f(hv.x), v1 = bf2f(hv.y), v2 = bf2f(hv.z), v3 = bf2f(hv.w);
        const unsigned short* mp = msg + (size_t)s0 * HDIM + lane * 4;
        for (int q = 0; q < n; ++q) {
            ushort4 m = *(const ushort4*)(mp + (size_t)q * HDIM);
            v0 += bf2f(m.x); v1 += bf2f(m.y); v2 += bf2f(m.z); v3 += bf2f(m.w);
        }
        v0 = fmaxf(v0, 0.f); v1 = fmaxf(v1, 0.f);
        v2 = fmaxf(v2, 0.f); v3 = fmaxf(v3, 0.f);
        float pp = v0 * wv.x + v1 * wv.y + v2 * wv.z + v3 * wv.w;
        for (int off = 32; off >= 1; off >>= 1) pp += __shfl_down(pp, off, 64);
        float tot = __shfl(pp, 0, 64);
        float sig = 1.0f / (1.0f + expf(-(tot + wb)));
        a0 += sig * v0; a1 += sig * v1; a2 += sig * v2; a3 += sig * v3;
    }
    sacc[wave][lane * 4 + 0] = a0; sacc[wave][lane * 4 + 1] = a1;
    sacc[wave][lane * 4 + 2] = a2; sacc[wave][lane * 4 + 3] = a3;
    __syncthreads();
    emb[(size_t)g * HDIM + t] = sacc[0][t] + sacc[1][t] + sacc[2][t] + sacc[3][t];
}

// fallback pool (fp32 h input)
__global__ void pool_kernel(const float* __restrict__ h, const int* __restrict__ batch,
                            const float* __restrict__ wsw, const float* __restrict__ wsb,
                            float* __restrict__ emb) {
    int i = blockIdx.x;
    int t = threadIdx.x;
    float v = fmaxf(h[(size_t)i * HDIM + t], 0.f);
    float p = v * wsw[t];
    for (int off = 32; off >= 1; off >>= 1) p += __shfl_down(p, off, 64);
    __shared__ float red[4];
    __shared__ float ssig;
    if ((t & 63) == 0) red[t >> 6] = p;
    __syncthreads();
    if (t == 0) {
        float s = red[0] + red[1] + red[2] + red[3] + wsb[0];
        ssig = 1.0f / (1.0f + expf(-s));
    }
    __syncthreads();
    atomicAdd(&emb[(size_t)batch[i] * HDIM + t], ssig * v);
}

__global__ void mlp_kernel(const float* __restrict__ emb,
                           const float* __restrict__ m1w, const float* __restrict__ m1b,
                           const float* __restrict__ m2w, const float* __restrict__ m2b,
                           const float* __restrict__ m3w, const float* __restrict__ m3b,
                           const float* __restrict__ ow,  const float* __restrict__ ob,
                           float* __restrict__ out) {
    int g = blockIdx.x;
    int t = threadIdx.x; // 64 threads = 1 wave
    __shared__ float e[HDIM];
    __shared__ float z1[64], z2[64];
    for (int idx = t; idx < HDIM; idx += 64) e[idx] = emb[(size_t)g * HDIM + idx];
    __syncthreads();
    float a = m1b[t];
    for (int k = 0; k < HDIM; ++k) a += e[k] * m1w[k * 64 + t];
    z1[t] = fmaxf(a, 0.f);
    __syncthreads();
    a = m2b[t];
    for (int k = 0; k < 64; ++k) a += z1[k] * m2w[k * 64 + t];
    z2[t] = fmaxf(a, 0.f);
    __syncthreads();
    a = m3b[t];
    for (int k = 0; k < 64; ++k) a += z2[k] * m3w[k * 64 + t];
    float p = a * ow[t];
    for (int off = 32; off >= 1; off >>= 1) p += __shfl_down(p, off, 64);
    if (t == 0) out[g] = p + ob[0];
}

extern "C" void kernel_launch(void* const* d_in, const int* in_sizes, int n_in,
                              void* d_out, int out_size, void* d_ws, size_t ws_size,
                              hipStream_t stream) {
    const float* x     = (const float*)d_in[0];
    const int*   ei    = (const int*)d_in[1];
    const int*   src   = ei;
    const int*   dst   = ei + E_REAL;
    const int*   et    = (const int*)d_in[2];
    const int*   batch = (const int*)d_in[3];
    const float* W1    = (const float*)d_in[4];
    const float* root1 = (const float*)d_in[5];
    const float* b1    = (const float*)d_in[6];
    const float* W2    = (const float*)d_in[7];
    const float* root2 = (const float*)d_in[8];
    const float* b2    = (const float*)d_in[9];
    const float* wsw   = (const float*)d_in[10];
    const float* wsb   = (const float*)d_in[11];
    const float* m1w   = (const float*)d_in[12];
    const float* m1b   = (const float*)d_in[13];
    const float* m2w   = (const float*)d_in[14];
    const float* m2b   = (const float*)d_in[15];
    const float* m3w   = (const float*)d_in[16];
    const float* m3b   = (const float*)d_in[17];
    const float* ow    = (const float*)d_in[18];
    const float* ob    = (const float*)d_in[19];

    char* ws = (char*)d_ws;
    size_t off = 0;
    auto alloc = [&](size_t bytes) {
        void* p = ws + off;
        off = (off + bytes + 255) & ~(size_t)255;
        return p;
    };
    // common buffers
    int*   cnt       = (int*)alloc((size_t)N_NODES * NREL * 4);     // 13.0 MB
    int*   blockHist = (int*)alloc((size_t)TOT_HIST * 4);
    int*   baseArr   = (int*)alloc((size_t)TOT_HIST * 4);
    int*   perm      = (int*)alloc((size_t)E_REAL * 4);             // 0.8 MB
    int*   srcOf     = (int*)alloc((size_t)E_REAL * 4);             // 0.8 MB
    float* wOf       = (float*)alloc((size_t)E_REAL * 4);           // 0.8 MB
    int*   relStartA = (int*)alloc(NREL * 4);
    int*   relTotA   = (int*)alloc(NREL * 4);
    int*   pbStartA  = (int*)alloc(NREL * 4);
    int*   relOfBlk  = (int*)alloc(MAX_PB * 4);
    int*   npb       = (int*)alloc(4);
    int*   psumA     = (int*)alloc(64 * 4);
    int*   psumB     = (int*)alloc(64 * 4);
    unsigned short* xb  = (unsigned short*)alloc((size_t)N_NODES * 128 * 2);    // 12.8 MB
    unsigned short* w1b = (unsigned short*)alloc((size_t)NREL * 256 * 128 * 2); // 4.3 MB
    unsigned short* w2b = (unsigned short*)alloc((size_t)NREL * 256 * 256 * 2); // 8.5 MB
    unsigned short* r1b = (unsigned short*)alloc((size_t)256 * 128 * 2);
    unsigned short* r2b = (unsigned short*)alloc((size_t)256 * 256 * 2);
    unsigned short* h1b = (unsigned short*)alloc((size_t)N_NODES * HDIM * 2);   // 25.6 MB
    float* emb = (float*)alloc((size_t)NGRAPH * HDIM * 4);                       // 1.6 MB
    size_t off_common = off;

    // fast-path extras
    unsigned short* hinit = (unsigned short*)alloc((size_t)N_NODES * HDIM * 2); // 25.6 MB
    unsigned short* msg   = (unsigned short*)alloc((size_t)E_REAL * HDIM * 2);  // 102.4 MB
    int* qofp    = (int*)alloc((size_t)E_REAL * 4);
    int* cntD    = (int*)alloc((size_t)N_NODES * 4);
    int* startD  = (int*)alloc((size_t)N_NODES * 4);
    int* cursorD = (int*)alloc((size_t)N_NODES * 4);
    size_t need_fast = off;

    float* hf = nullptr;
    bool fast = (ws_size >= need_fast);
    if (!fast) {
        off = off_common;
        hf = (float*)alloc((size_t)N_NODES * HDIM * 4);  // 51.2 MB
        char* hh = (char*)hf;   // dst structures alias hf (used before hf written)
        qofp    = (int*)hh;                                 hh += (size_t)E_REAL * 4;
        cntD    = (int*)hh;                                 hh += (size_t)N_NODES * 4;
        startD  = (int*)hh;                                 hh += (size_t)N_NODES * 4;
        cursorD = (int*)hh;
        hinit = h1b;  // unused sink
        msg = h1b;    // unused sink
    }

    hipMemsetAsync(cnt, 0, (size_t)N_NODES * NREL * 4, stream);
    hipMemsetAsync(cntD, 0, (size_t)N_NODES * 4, stream);

    count_kernel<<<NB_CNT, 256, 0, stream>>>(src, dst, et, cnt, blockHist, cntD);
    scan_part2<<<NSA + NSB, 1024, 0, stream>>>(blockHist, cntD, psumA, psumB);
    scan_apply2<<<NSA + NSB, 1024, 0, stream>>>(blockHist, cntD, psumA, psumB,
                                                baseArr, startD, cursorD);
    meta_kernel<<<1, 1024, 0, stream>>>(baseArr, relStartA, relTotA, pbStartA, relOfBlk, npb);
    scatter_sorted<<<NB_R, 256, 0, stream>>>(src, dst, et, baseArr, cnt,
                                             perm, cursorD, qofp, srcOf, wOf);

    cvt_all<<<(CVT_TOT + 255) / 256, 256, 0, stream>>>(x, W1, W2, root1, root2,
                                                       xb, w1b, w2b, r1b, r2b);

    if (fast) {
        // layer 1
        init_gemm<128><<<GRID_I, 256, 0, stream>>>(xb, r1b, w1b, b1, hinit, cnt);
        edge_msg<128><<<MAX_PB, 256, 0, stream>>>(xb, w1b, msg,
            srcOf, wOf, qofp, relOfBlk, pbStartA, relStartA, relTotA, npb);
        reduce_kernel<<<(N_NODES + 7) / 8, 256, 0, stream>>>(hinit, msg, startD, cntD, h1b);
        // layer 2: reduce fused with pooling, h2 never materialized
        init_gemm<256><<<GRID_I, 256, 0, stream>>>(h1b, r2b, w2b, b2, hinit, cnt);
        edge_msg<256><<<MAX_PB, 256, 0, stream>>>(h1b, w2b, msg,
            srcOf, wOf, qofp, relOfBlk, pbStartA, relStartA, relTotA, npb);
        reduce_pool<<<NGRAPH, 256, 0, stream>>>(hinit, msg, startD, cntD,
                                                batch, wsw, wsb, emb);
    } else {
        hipMemsetAsync(emb, 0, (size_t)NGRAPH * HDIM * 4, stream);
        mfma_gemm<128, 0><<<GRID_I, 256, 0, stream>>>(xb, r1b, w1b, b1, hf,
            nullptr, nullptr, nullptr, cnt, nullptr, nullptr, nullptr, nullptr, nullptr);
        mfma_gemm<128, 1><<<MAX_PB, 256, 0, stream>>>(xb, w1b, nullptr, nullptr, hf,
            perm, src, dst, cnt, relOfBlk, pbStartA, relStartA, relTotA, npb);
        cvt_rows<<<(N_NODES * HDIM / 8 + 255) / 256, 256, 0, stream>>>(hf, h1b, N_NODES * HDIM / 8, 1);
        mfma_gemm<256, 0><<<GRID_I, 256, 0, stream>>>(h1b, r2b, w2b, b2, hf,
            nullptr, nullptr, nullptr, cnt, nullptr, nullptr, nullptr, nullptr, nullptr);
        mfma_gemm<256, 1><<<MAX_PB, 256, 0, stream>>>(h1b, w2b, nullptr, nullptr, hf,
            perm, src, dst, cnt, relOfBlk, pbStartA, relStartA, relTotA, npb);
        pool_kernel<<<N_NODES, 256, 0, stream>>>(hf, batch, wsw, wsb, emb);
    }
    mlp_kernel<<<NGRAPH, 64, 0, stream>>>(emb, m1w, m1b, m2w, m2b, m3w, m3b, ow, ob, (float*)d_out);
}